// Round 1
// baseline (364.783 us; speedup 1.0000x reference)
//
#include <hip/hip_runtime.h>
#include <hip/hip_bf16.h>

// Dims from the reference
#define D_FEAT 128
#define HIDDEN 16
#define NCLS 40

// ---------------------------------------------------------------------------
// Kernel 1: yl = x @ W_l ; yr = x @ W_r   (N x 128) @ (128 x 16) twice, fused
// 32 rows per block, 256 threads: thread = (row r = tid>>3, quad oq = tid&7)
// each thread computes 4 outputs (float4) of the 32 combined output columns.
// ---------------------------------------------------------------------------
__global__ __launch_bounds__(256) void lin_kernel(
    const float* __restrict__ x,
    const float* __restrict__ Wl, const float* __restrict__ Wr,
    float* __restrict__ yl, float* __restrict__ yr, int N) {
  __shared__ float sW[D_FEAT][8][4];   // [k][oq][j] : col o = oq*4+j  (16KB)
  __shared__ float sx[32][132];        // padded: bank = (4r+k)%32, conflict-free

  int tid = threadIdx.x;
  for (int idx = tid; idx < D_FEAT * 32; idx += 256) {
    int k = idx >> 5, o = idx & 31;
    float v = (o < 16) ? Wl[k * 16 + o] : Wr[k * 16 + (o - 16)];
    sW[k][o >> 2][o & 3] = v;
  }

  int row0 = blockIdx.x * 32;
  for (int q = tid; q < 32 * 32; q += 256) {   // 32 rows x 32 float4
    int r = q >> 5, k4 = q & 31;
    int row = row0 + r;
    float4 v = make_float4(0.f, 0.f, 0.f, 0.f);
    if (row < N) v = *(const float4*)(x + (size_t)row * D_FEAT + k4 * 4);
    *(float4*)(&sx[r][k4 * 4]) = v;
  }
  __syncthreads();

  int r = tid >> 3, oq = tid & 7;
  int row = row0 + r;
  if (row < N) {
    float4 acc = make_float4(0.f, 0.f, 0.f, 0.f);
#pragma unroll
    for (int k = 0; k < D_FEAT; ++k) {
      float xv = sx[r][k];
      const float4 w = *(const float4*)(&sW[k][oq][0]);
      acc.x += xv * w.x; acc.y += xv * w.y;
      acc.z += xv * w.z; acc.w += xv * w.w;
    }
    if (oq < 4)
      *(float4*)(yl + (size_t)row * 16 + oq * 4) = acc;
    else
      *(float4*)(yr + (size_t)row * 16 + (oq - 4) * 4) = acc;
  }
}

// ---------------------------------------------------------------------------
// Kernel 2: zero agg (N*16) + deg (N) — contiguous N*17 floats
// ---------------------------------------------------------------------------
__global__ __launch_bounds__(256) void zero_kernel(float4* __restrict__ p, int nvec) {
  int i = blockIdx.x * 256 + threadIdx.x;
  if (i < nvec) p[i] = make_float4(0.f, 0.f, 0.f, 0.f);
}

// ---------------------------------------------------------------------------
// Kernel 3: scatter — 16 threads per edge
//   agg[dst][f] += yl[src][f] ;  deg[dst] += 1
// ---------------------------------------------------------------------------
__global__ __launch_bounds__(256) void scatter_kernel(
    const int* __restrict__ src, const int* __restrict__ dst,
    const float* __restrict__ yl, float* __restrict__ agg,
    float* __restrict__ deg, int E) {
  int gid = blockIdx.x * 256 + threadIdx.x;
  int e = gid >> 4;
  if (e >= E) return;
  int f = gid & 15;
  int s = src[e], d = dst[e];
  atomicAdd(&agg[(size_t)d * 16 + f], yl[(size_t)s * 16 + f]);
  if (f == 0) atomicAdd(&deg[d], 1.0f);
}

// ---------------------------------------------------------------------------
// Kernel 4: per-node finish: mean, +b_l+yr, relu, @W3+b3, log_softmax
// one node per thread; LDS-staged coalesced output
// ---------------------------------------------------------------------------
__global__ __launch_bounds__(256) void finish_kernel(
    const float* __restrict__ agg, const float* __restrict__ deg,
    const float* __restrict__ yr, const float* __restrict__ bl,
    const float* __restrict__ W3, const float* __restrict__ b3,
    float* __restrict__ out, int N) {
  __shared__ float sW3[16 * NCLS];
  __shared__ float sb3[NCLS];
  __shared__ float sbl[16];
  __shared__ float slog[256][NCLS + 1];   // pad 41: bank=(9*t+c)%32, ~conflict-free

  int tid = threadIdx.x;
  for (int idx = tid; idx < 16 * NCLS; idx += 256) sW3[idx] = W3[idx];
  if (tid < NCLS) sb3[tid] = b3[tid];
  if (tid < 16) sbl[tid] = bl[tid];
  __syncthreads();

  int row0 = blockIdx.x * 256;
  int n = row0 + tid;
  if (n < N) {
    float inv = 1.0f / fmaxf(deg[n], 1.0f);
    float h[16];
#pragma unroll
    for (int k = 0; k < 16; ++k)
      h[k] = fmaxf(agg[(size_t)n * 16 + k] * inv + sbl[k] + yr[(size_t)n * 16 + k], 0.0f);

    float lg[NCLS];
#pragma unroll
    for (int c = 0; c < NCLS; ++c) lg[c] = sb3[c];
#pragma unroll
    for (int k = 0; k < 16; ++k) {
      float hv = h[k];
#pragma unroll
      for (int c = 0; c < NCLS; ++c) lg[c] += hv * sW3[k * NCLS + c];
    }

    float m = lg[0];
#pragma unroll
    for (int c = 1; c < NCLS; ++c) m = fmaxf(m, lg[c]);
    float ssum = 0.f;
#pragma unroll
    for (int c = 0; c < NCLS; ++c) ssum += __expf(lg[c] - m);
    float lse = m + __logf(ssum);
#pragma unroll
    for (int c = 0; c < NCLS; ++c) slog[tid][c] = lg[c] - lse;
  }
  __syncthreads();

  int cnt = min(256, N - row0);
  int total = cnt * NCLS;
  for (int idx = tid; idx < total; idx += 256) {
    int r = idx / NCLS, c = idx - r * NCLS;
    out[(size_t)row0 * NCLS + idx] = slog[r][c];
  }
}

// ---------------------------------------------------------------------------
extern "C" void kernel_launch(void* const* d_in, const int* in_sizes, int n_in,
                              void* d_out, int out_size, void* d_ws, size_t ws_size,
                              hipStream_t stream) {
  const float* x   = (const float*)d_in[0];
  const int* eidx  = (const int*)d_in[1];
  const float* Wl  = (const float*)d_in[2];
  const float* bl  = (const float*)d_in[3];
  const float* Wr  = (const float*)d_in[4];
  const float* W3  = (const float*)d_in[5];
  const float* b3  = (const float*)d_in[6];
  float* out = (float*)d_out;

  int N = in_sizes[0] / D_FEAT;
  int E = in_sizes[1] / 2;
  const int* src = eidx;
  const int* dst = eidx + E;

  // workspace layout (floats)
  size_t n16 = (size_t)N * 16;
  float* yl  = (float*)d_ws;               // N*16
  float* yr  = yl + n16;                   // N*16
  float* agg = yr + n16;                   // N*16
  float* deg = agg + n16;                  // N      (contiguous with agg)

  // K1: projections
  int nb1 = (N + 31) / 32;
  lin_kernel<<<nb1, 256, 0, stream>>>(x, Wl, Wr, yl, yr, N);

  // K2: zero agg+deg  (N*17 floats, divisible by 4 when N%4==0; round up)
  int nvec = (int)((n16 + (size_t)N + 3) / 4);
  zero_kernel<<<(nvec + 255) / 256, 256, 0, stream>>>((float4*)agg, nvec);

  // K3: scatter (16 threads / edge)
  long long tot = (long long)E * 16;
  int nb3 = (int)((tot + 255) / 256);
  scatter_kernel<<<nb3, 256, 0, stream>>>(src, dst, yl, agg, deg, E);

  // K4: finish
  int nb4 = (N + 255) / 256;
  finish_kernel<<<nb4, 256, 0, stream>>>(agg, deg, yr, bl, W3, b3, out, N);
}